// Round 1
// baseline (348.305 us; speedup 1.0000x reference)
//
#include <hip/hip_runtime.h>
#include <hip/hip_bf16.h>

#define N_NODES 100000
#define N_EDGES 1250000
#define D_FEAT  64

// One wave (64 lanes) per edge: lane = feature index.
// Gather x[src*64 + lane] (coalesced 256B), atomicAdd into out[dst*64 + lane].
__global__ __launch_bounds__(256) void onehop_scatter_add(
    const float* __restrict__ x,
    const int* __restrict__ edge_src,   // edge_index[0, :]
    const int* __restrict__ edge_dst,   // edge_index[1, :]
    float* __restrict__ out)
{
    const int tid  = blockIdx.x * blockDim.x + threadIdx.x;
    const int edge = tid >> 6;          // wave per edge
    const int feat = tid & 63;
    if (edge >= N_EDGES) return;

    const int s = edge_src[edge];
    const int d = edge_dst[edge];

    const float v = x[(size_t)s * D_FEAT + feat];
    atomicAdd(&out[(size_t)d * D_FEAT + feat], v);
}

extern "C" void kernel_launch(void* const* d_in, const int* in_sizes, int n_in,
                              void* d_out, int out_size, void* d_ws, size_t ws_size,
                              hipStream_t stream) {
    const float* x = (const float*)d_in[0];
    const int* edge_index = (const int*)d_in[1];   // [2, N_EDGES] flat, int32 per harness
    float* out = (float*)d_out;

    // Zero the output (harness poisons it with 0xAA before every launch).
    hipMemsetAsync(d_out, 0, (size_t)out_size * sizeof(float), stream);

    const int total_threads = N_EDGES * 64;
    const int block = 256;
    const int grid = (total_threads + block - 1) / block;
    onehop_scatter_add<<<grid, block, 0, stream>>>(
        x, edge_index, edge_index + N_EDGES, out);
}